// Round 6
// baseline (196.537 us; speedup 1.0000x reference)
//
#include <hip/hip_runtime.h>

// BackwardRPM: 16384 independent solves, 200 steps of
//   u <- clip(u - LR * (R^T (R (tanh(u W1 + b1) W2 + b2 - spec)))[:6])
// Algebra: Qs = -LR * W2 R^T R[:, :6] (64x6), Ss = -LR * R[:, :6]^T R (6x40),
//   es = Ss (b2 - spec) per sample. Step: t = u W1 + b1; h = tanh(t);
//   u = clip(u + h Qs + es).
// Folds: tanh(t) = 1 - 2*rcp(e^{2t}+1); W1,b1 pre-scaled by K=2*log2(e);
//   h Qs = colsum(Qs) + r @ (-2 Qs) -> colsum folded into es.
// R5-R8: VALU path bottomed at 97.8us (L=4, busy 822cy/wave/step).
// R9: MFMA offload of r @ (-2Qs) with 2-way bf16 split -> FAILED absmax
//   0.14: the iteration is chaotic for some samples (amplification ~1e5
//   over 200 steps); 2-split injects 2^-18-grade noise (1e-6/step), 10x
//   over fp32 grade. NOT a layout failure signature (that would be O(0.5)).
// R10 (this round): SAME layout, 3-way bf16 split of both operands
//   (Q limbs precomputed; r split per step, 11 ops/pair). Kept products:
//   (1,1),(2,1),(3,1),(1,2),(2,2),(1,3) per tile -> residual 2^-27, below
//   fp32 rounding. 12 MFMAs/step in 4 chains of 3 on the idle matrix pipe.
//   u-buffer reorganized to [j][sample]: D-layout write = ONE aligned
//   ds_write_b128 (was 4x b32 with 4-way bank conflict); reads are 6
//   broadcast b32, conflict-free. DPP butterfly fully gone.

static constexpr float LR_ = 0.01f;

typedef float v2f   __attribute__((ext_vector_type(2)));
typedef float f32x4 __attribute__((ext_vector_type(4)));
typedef int   i32x4 __attribute__((ext_vector_type(4)));
typedef short s16x8 __attribute__((ext_vector_type(8)));

__device__ __forceinline__ void pin2(v2f& x)   { asm volatile("" : "+v"(x)); }
__device__ __forceinline__ void pin4(i32x4& x) { asm volatile("" : "+v"(x)); }
__device__ __forceinline__ void pinf4(f32x4& x){ asm volatile("" : "+v"(x)); }

// v_pk_fma_f32 with src0 broadcast from lo/hi half (VOP3P op_sel).
#define PK_FMA_LO(T, U, W)                                                   \
    asm("v_pk_fma_f32 %0, %1, %2, %0 op_sel:[0,0,0] op_sel_hi:[0,1,1]"       \
        : "+v"(T) : "v"(U), "v"(W))
#define PK_FMA_HI(T, U, W)                                                   \
    asm("v_pk_fma_f32 %0, %1, %2, %0 op_sel:[1,0,0] op_sel_hi:[1,1,1]"       \
        : "+v"(T) : "v"(U), "v"(W))

__device__ __forceinline__ unsigned cvt_pk_bf16(float lo, float hi) {
    unsigned d;
    asm("v_cvt_pk_bf16_f32 %0, %1, %2" : "=v"(d) : "v"(lo), "v"(hi));
    return d;
}
__device__ __forceinline__ float lo16f(unsigned p) {
    return __int_as_float((int)(p << 16));
}
__device__ __forceinline__ float hi16f(unsigned p) {
    return __int_as_float((int)(p & 0xffff0000u));
}
// 3-limb bf16 split of a pair of f32: x = lo(p1)+lo(p2)+lo(p3) to ~2^-27.
__device__ __forceinline__ void split3(float x, float y,
                                       unsigned& p1, unsigned& p2, unsigned& p3) {
    p1 = cvt_pk_bf16(x, y);
    float dx = x - lo16f(p1), dy = y - hi16f(p1);
    p2 = cvt_pk_bf16(dx, dy);
    p3 = cvt_pk_bf16(dx - lo16f(p2), dy - hi16f(p2));
}
__device__ __forceinline__ s16x8 mk8(unsigned a, unsigned b, unsigned c, unsigned d) {
    return __builtin_bit_cast(s16x8, (i32x4){(int)a, (int)b, (int)c, (int)d});
}

__global__ __launch_bounds__(256)
__attribute__((amdgpu_waves_per_eu(1, 1)))
void solve_k(
    const float* __restrict__ spec, const float* __restrict__ W1,
    const float* __restrict__ b1,   const float* __restrict__ W2,
    const float* __restrict__ b2,   const float* __restrict__ R,
    float* __restrict__ out, int batch)
{
    __shared__ float sQs[64 * 7];  // Qs[i][j] = sQs[i*7+j] (includes -LR)
    __shared__ float sSs[240];     // Ss[j][k] = sSs[j*40+k] (includes -LR)
    // per-wave u, [j][sample] so the D-layout write is one b128
    __shared__ __attribute__((aligned(16))) float sUT[4][6][16];

    const int t = threadIdx.x;

    // ---- per-block setup: Qs = -LR * W2 R^T R6, Ss = -LR * R6^T R ----
    if (t < 64) {
        float M[8];
        #pragma unroll
        for (int p = 0; p < 8; ++p) {
            float acc = 0.f;
            for (int k = 0; k < 40; ++k) acc = fmaf(W2[t*40+k], R[p*40+k], acc);
            M[p] = acc;
        }
        #pragma unroll
        for (int j = 0; j < 6; ++j) {
            float acc = 0.f;
            #pragma unroll
            for (int p = 0; p < 8; ++p) acc = fmaf(M[p], R[p*40+j], acc);
            sQs[t*7+j] = -LR_ * acc;
        }
    } else {
        for (int idx = t - 64; idx < 240; idx += 192) {
            int j = idx / 40, k = idx % 40;
            float acc = 0.f;
            #pragma unroll
            for (int p = 0; p < 8; ++p) acc = fmaf(R[p*40+j], R[p*40+k], acc);
            sSs[idx] = -LR_ * acc;
        }
    }
    __syncthreads();

    // ---- lane roles (unchanged from R9) ----
    const int w     = t >> 6;        // wave in block
    const int l     = t & 63;        // lane
    const int col   = l & 15;        // A-row = tanh sample; B/D col = j
    const int grp   = l >> 4;        // k-chunk group; D row-group
    const int sbase = blockIdx.x * 64 + w * 16;

    const float K = 2.8853900817779268f;  // 2*log2(e)

    // W1K/b1K for this lane's 16 units: unit = 32*tile + grp*8 + 2rp (+1)
    v2f w1kp[6][2][4], b1kp[2][4];
    #pragma unroll
    for (int j = 0; j < 6; ++j)
        #pragma unroll
        for (int tile = 0; tile < 2; ++tile)
            #pragma unroll
            for (int rp = 0; rp < 4; ++rp) {
                int uu = 32*tile + grp*8 + 2*rp;
                w1kp[j][tile][rp].x = K * W1[j*64 + uu];
                w1kp[j][tile][rp].y = K * W1[j*64 + uu + 1];
            }
    #pragma unroll
    for (int tile = 0; tile < 2; ++tile)
        #pragma unroll
        for (int rp = 0; rp < 4; ++rp) {
            int uu = 32*tile + grp*8 + 2*rp;
            b1kp[tile][rp].x = K * b1[uu];
            b1kp[tile][rp].y = K * b1[uu + 1];
        }

    // B fragments: 3-limb bf16 split of (-2 * Qs[unit][col]), 0 for col>=6.
    i32x4 B1W[2], B2W[2], B3W[2];
    #pragma unroll
    for (int tile = 0; tile < 2; ++tile) {
        unsigned w1_[4], w2_[4], w3_[4];
        #pragma unroll
        for (int rp = 0; rp < 4; ++rp) {
            int uu = 32*tile + grp*8 + 2*rp;
            float q0 = 0.f, q1 = 0.f;
            if (col < 6) {
                q0 = -2.f * sQs[uu*7 + col];
                q1 = -2.f * sQs[(uu+1)*7 + col];
            }
            split3(q0, q1, w1_[rp], w2_[rp], w3_[rp]);
        }
        B1W[tile] = (i32x4){(int)w1_[0], (int)w1_[1], (int)w1_[2], (int)w1_[3]};
        B2W[tile] = (i32x4){(int)w2_[0], (int)w2_[1], (int)w2_[2], (int)w2_[3]};
        B3W[tile] = (i32x4){(int)w3_[0], (int)w3_[1], (int)w3_[2], (int)w3_[3]};
    }

    // esD[q] = colsum(Qs[:,col]) + sum_k Ss[col][k]*(b2[k]-spec[row_q][k])
    float esD[4] = {0.f, 0.f, 0.f, 0.f};
    if (col < 6) {
        float qcol = 0.f;
        for (int i = 0; i < 64; ++i) qcol += sQs[i*7 + col];
        #pragma unroll
        for (int q = 0; q < 4; ++q) {
            int srow = sbase + grp*4 + q;
            int sl2 = srow < batch ? srow : 0;
            const float* sp = spec + sl2 * 40;
            float acc = qcol;
            for (int k = 0; k < 40; ++k)
                acc = fmaf(b2[k] - sp[k], sSs[col*40 + k], acc);
            esD[q] = acc;
        }
    }

    f32x4 uD = (col < 6) ? (f32x4){0.5f, 0.5f, 0.5f, 0.5f}
                         : (f32x4){0.f, 0.f, 0.f, 0.f};
    f32x4 esD4 = {esD[0], esD[1], esD[2], esD[3]};

    v2f u2[3];
    u2[0] = u2[1] = u2[2] = (v2f){0.5f, 0.5f};

    // pin loop-invariants (budget 512 VGPR at 1 wave/EU)
    #pragma unroll
    for (int j = 0; j < 6; ++j)
        #pragma unroll
        for (int tile = 0; tile < 2; ++tile)
            #pragma unroll
            for (int rp = 0; rp < 4; ++rp) pin2(w1kp[j][tile][rp]);
    #pragma unroll
    for (int tile = 0; tile < 2; ++tile)
        #pragma unroll
        for (int rp = 0; rp < 4; ++rp) pin2(b1kp[tile][rp]);
    pin4(B1W[0]); pin4(B1W[1]); pin4(B2W[0]); pin4(B2W[1]);
    pin4(B3W[0]); pin4(B3W[1]); pinf4(esD4);

    const s16x8 B1_0 = __builtin_bit_cast(s16x8, B1W[0]);
    const s16x8 B1_1 = __builtin_bit_cast(s16x8, B1W[1]);
    const s16x8 B2_0 = __builtin_bit_cast(s16x8, B2W[0]);
    const s16x8 B2_1 = __builtin_bit_cast(s16x8, B2W[1]);
    const s16x8 B3_0 = __builtin_bit_cast(s16x8, B3W[0]);
    const s16x8 B3_1 = __builtin_bit_cast(s16x8, B3W[1]);
    const f32x4 zero4 = {0.f, 0.f, 0.f, 0.f};

    for (int step = 0; step < 200; ++step) {
        // tt = b1K + u W1K for sample=col, 16 units (8 pairs, both tiles)
        v2f tt[2][4];
        #pragma unroll
        for (int tile = 0; tile < 2; ++tile)
            #pragma unroll
            for (int rp = 0; rp < 4; ++rp) tt[tile][rp] = b1kp[tile][rp];
        #pragma unroll
        for (int jp = 0; jp < 3; ++jp) {
            #pragma unroll
            for (int tile = 0; tile < 2; ++tile)
                #pragma unroll
                for (int rp = 0; rp < 4; ++rp)
                    PK_FMA_LO(tt[tile][rp], u2[jp], w1kp[2*jp][tile][rp]);
            #pragma unroll
            for (int tile = 0; tile < 2; ++tile)
                #pragma unroll
                for (int rp = 0; rp < 4; ++rp)
                    PK_FMA_HI(tt[tile][rp], u2[jp], w1kp[2*jp+1][tile][rp]);
        }
        // r = rcp(exp2(tt)+1); 3-limb bf16 split per pair
        unsigned a1[2][4], a2[2][4], a3[2][4];
        #pragma unroll
        for (int tile = 0; tile < 2; ++tile)
            #pragma unroll
            for (int rp = 0; rp < 4; ++rp) {
                v2f e;
                e.x = __builtin_amdgcn_exp2f(tt[tile][rp].x);
                e.y = __builtin_amdgcn_exp2f(tt[tile][rp].y);
                e += (v2f){1.f, 1.f};
                float rx = __builtin_amdgcn_rcpf(e.x);
                float ry = __builtin_amdgcn_rcpf(e.y);
                split3(rx, ry, a1[tile][rp], a2[tile][rp], a3[tile][rp]);
            }
        s16x8 A1_0 = mk8(a1[0][0], a1[0][1], a1[0][2], a1[0][3]);
        s16x8 A2_0 = mk8(a2[0][0], a2[0][1], a2[0][2], a2[0][3]);
        s16x8 A3_0 = mk8(a3[0][0], a3[0][1], a3[0][2], a3[0][3]);
        s16x8 A1_1 = mk8(a1[1][0], a1[1][1], a1[1][2], a1[1][3]);
        s16x8 A2_1 = mk8(a2[1][0], a2[1][1], a2[1][2], a2[1][3]);
        s16x8 A3_1 = mk8(a3[1][0], a3[1][1], a3[1][2], a3[1][3]);

        // D = (u + es) + r @ (-2Qs); kept limb products: (1,1),(2,1),(3,1),
        // (1,2),(2,2),(1,3) per tile -> 12 MFMAs in 4 chains of 3
        f32x4 C = uD + esD4;
        f32x4 c00 = __builtin_amdgcn_mfma_f32_16x16x32_bf16(A1_0, B1_0, C, 0, 0, 0);
        c00 = __builtin_amdgcn_mfma_f32_16x16x32_bf16(A2_0, B1_0, c00, 0, 0, 0);
        c00 = __builtin_amdgcn_mfma_f32_16x16x32_bf16(A3_0, B1_0, c00, 0, 0, 0);
        f32x4 c01 = __builtin_amdgcn_mfma_f32_16x16x32_bf16(A1_0, B2_0, zero4, 0, 0, 0);
        c01 = __builtin_amdgcn_mfma_f32_16x16x32_bf16(A2_0, B2_0, c01, 0, 0, 0);
        c01 = __builtin_amdgcn_mfma_f32_16x16x32_bf16(A1_0, B3_0, c01, 0, 0, 0);
        f32x4 c10 = __builtin_amdgcn_mfma_f32_16x16x32_bf16(A1_1, B1_1, zero4, 0, 0, 0);
        c10 = __builtin_amdgcn_mfma_f32_16x16x32_bf16(A2_1, B1_1, c10, 0, 0, 0);
        c10 = __builtin_amdgcn_mfma_f32_16x16x32_bf16(A3_1, B1_1, c10, 0, 0, 0);
        f32x4 c11 = __builtin_amdgcn_mfma_f32_16x16x32_bf16(A1_1, B2_1, zero4, 0, 0, 0);
        c11 = __builtin_amdgcn_mfma_f32_16x16x32_bf16(A2_1, B2_1, c11, 0, 0, 0);
        c11 = __builtin_amdgcn_mfma_f32_16x16x32_bf16(A1_1, B3_1, c11, 0, 0, 0);
        f32x4 D = (c00 + c01) + (c10 + c11);
        #pragma unroll
        for (int q = 0; q < 4; ++q)
            uD[q] = __builtin_amdgcn_fmed3f(D[q], 0.f, 1.f);

        // redistribute u: lane (col<6, grp) holds u[grp*4+q][col] -> one
        // aligned ds_write_b128 into sUT[w][col][grp*4..]
        if (col < 6)
            *(f32x4*)&sUT[w][col][grp*4] = uD;
        // same-wave read-back (6 broadcast b32, conflict-free)
        u2[0].x = sUT[w][0][col]; u2[0].y = sUT[w][1][col];
        u2[1].x = sUT[w][2][col]; u2[1].y = sUT[w][3][col];
        u2[2].x = sUT[w][4][col]; u2[2].y = sUT[w][5][col];
    }

    // epilogue: sUT[w][j][sample] holds u_200; 96 floats/wave
    #pragma unroll
    for (int it = 0; it < 2; ++it) {
        int idx = l + 64*it;
        if (idx < 96) {
            int srow = idx / 6;
            int j = idx - srow*6;
            int gs = sbase + srow;
            if (gs < batch) out[gs*6 + j] = sUT[w][j][srow];
        }
    }
}

extern "C" void kernel_launch(void* const* d_in, const int* in_sizes, int n_in,
                              void* d_out, int out_size, void* d_ws, size_t ws_size,
                              hipStream_t stream)
{
    const float* spec = (const float*)d_in[0];  // (B,40)
    const float* W1   = (const float*)d_in[1];  // (6,64)
    const float* b1   = (const float*)d_in[2];  // (64,)
    const float* W2   = (const float*)d_in[3];  // (64,40)
    const float* b2   = (const float*)d_in[4];  // (40,)
    const float* R    = (const float*)d_in[5];  // (8,40)
    int batch = in_sizes[0] / 40;

    int threads = batch * 4;
    int blocks  = (threads + 255) / 256;
    hipLaunchKernelGGL(solve_k, dim3(blocks), dim3(256), 0, stream,
                       spec, W1, b1, W2, b2, R, (float*)d_out, batch);
}

// Round 7
// 145.521 us; speedup vs baseline: 1.3506x; 1.3506x over previous
//
#include <hip/hip_runtime.h>

// BackwardRPM: 16384 independent solves, 200 steps of
//   u <- clip(u - LR * (R^T (R (tanh(u W1 + b1) W2 + b2 - spec)))[:6])
// Algebra: Qs = -LR * W2 R^T R[:, :6] (64x6), Ss = -LR * R[:, :6]^T R (6x40),
//   es = Ss (b2 - spec) per sample. Step: t = u W1 + b1; h = tanh(t);
//   u = clip(u + h Qs + es).
// Folds: tanh(t) = 1 - 2*rcp(e^{2t}+1); W1,b1 pre-scaled by K=2*log2(e);
//   h Qs -> colsum(Qs) folded into c2, Qs pre-scaled by -2.
// History: R5 DPP-asm/pair-rcp neutral. R6 L=16 regressed (-30%, issue-
//   bound not latency-bound). R7 op_sel broadcasts + split g-chains ->
//   110.9us. R8 L=4 (16 samples/wave, 1 wave/SIMD) -> 97.8us; busy 822cy
//   matches static model (pk_fma=4cy, trans=8cy), idle 352cy.
// R9/R10 MFMA offload: correctness proven (3-limb bf16 split = fp32 grade,
//   absmax at floor) but PERF LOSER: limb-split VALU cost == the g-FMAs it
//   replaces, plus serial LDS/MFMA latency exposed at 1 wave/SIMD (158us).
//   Rank-6 update too small for the matrix pipe. Reverted.
// R11 (this round): R8 + two-tile phase interleave + 2-step unroll.
//   Source-level software pipeline: trans(tile0) -> gA-FMAs interleaved
//   with trans(tile1) -> gB. Goal: fill the ~352cy of phase-transition
//   bubbles (trans block was clumped; at 1 wave/SIMD nothing else fills
//   joins). Arithmetic order per chain identical to R8 -> bit-identical.

static constexpr float LR_ = 0.01f;

typedef float v2f __attribute__((ext_vector_type(2)));

__device__ __forceinline__ void pin2(v2f& x) { asm volatile("" : "+v"(x)); }

// v_pk_fma_f32 with src0 broadcast from lo/hi half (VOP3P op_sel).
#define PK_FMA_LO(T, U, W)                                                   \
    asm("v_pk_fma_f32 %0, %1, %2, %0 op_sel:[0,0,0] op_sel_hi:[0,1,1]"       \
        : "+v"(T) : "v"(U), "v"(W))
#define PK_FMA_HI(T, U, W)                                                   \
    asm("v_pk_fma_f32 %0, %1, %2, %0 op_sel:[1,0,0] op_sel_hi:[1,1,1]"       \
        : "+v"(T) : "v"(U), "v"(W))
#define PK_MUL_LO(D, U, W)                                                   \
    asm("v_pk_mul_f32 %0, %1, %2 op_sel:[0,0] op_sel_hi:[0,1]"               \
        : "=v"(D) : "v"(U), "v"(W))

__global__ __launch_bounds__(256)
__attribute__((amdgpu_waves_per_eu(1, 1)))
void solve_k(
    const float* __restrict__ spec, const float* __restrict__ W1,
    const float* __restrict__ b1,   const float* __restrict__ W2,
    const float* __restrict__ b2,   const float* __restrict__ R,
    float* __restrict__ out, int batch)
{
    __shared__ float sQs[64 * 7];  // Qs[i][j] = sQs[i*7+j]
    __shared__ float sSs[240];     // Ss[j][k] = sSs[j*40+k] (includes -LR)

    const int t = threadIdx.x;

    // ---- per-block setup: Qs = -LR * W2 R^T R6, Ss = -LR * R6^T R ----
    if (t < 64) {
        float M[8];
        #pragma unroll
        for (int p = 0; p < 8; ++p) {
            float acc = 0.f;
            for (int k = 0; k < 40; ++k) acc = fmaf(W2[t*40+k], R[p*40+k], acc);
            M[p] = acc;
        }
        #pragma unroll
        for (int j = 0; j < 6; ++j) {
            float acc = 0.f;
            #pragma unroll
            for (int p = 0; p < 8; ++p) acc = fmaf(M[p], R[p*40+j], acc);
            sQs[t*7+j] = -LR_ * acc;
        }
    } else {
        for (int idx = t - 64; idx < 240; idx += 192) {
            int j = idx / 40, k = idx % 40;
            float acc = 0.f;
            #pragma unroll
            for (int p = 0; p < 8; ++p) acc = fmaf(R[p*40+j], R[p*40+k], acc);
            sSs[idx] = -LR_ * acc;
        }
    }
    __syncthreads();

    // ---- per-thread constants ----
    const int tid = blockIdx.x * 256 + t;
    const int s   = tid >> 2;    // sample (16 per wave, one per quad)
    const int sub = tid & 3;     // quarter of hidden dim
    const int ib  = sub * 16;    // 16 hidden units per lane
    const bool live = (s < batch);
    const int sl = live ? s : 0;

    const float K = 2.8853900817779268f;  // 2*log2(e)

    // W1 (6,64) row-major, pre-scaled by K, packed over hidden pairs p=0..7.
    v2f w1kp[6][8], b1kp[8];
    #pragma unroll
    for (int j = 0; j < 6; ++j)
        #pragma unroll
        for (int p = 0; p < 8; ++p) {
            w1kp[j][p].x = K * W1[j*64 + ib + 2*p];
            w1kp[j][p].y = K * W1[j*64 + ib + 2*p + 1];
        }
    #pragma unroll
    for (int p = 0; p < 8; ++p) {
        b1kp[p].x = K * b1[ib + 2*p];
        b1kp[p].y = K * b1[ib + 2*p + 1];
    }

    // qs2p[i][m] = -2 * Qs[ib+i][2m..2m+1];  qc[j] = sum_i Qs[ib+i][j]
    v2f qs2p[16][3];
    float qc[6];
    #pragma unroll
    for (int j = 0; j < 6; ++j) qc[j] = 0.f;
    #pragma unroll
    for (int i = 0; i < 16; ++i)
        #pragma unroll
        for (int m = 0; m < 3; ++m) {
            float a = sQs[(ib + i)*7 + 2*m];
            float b = sQs[(ib + i)*7 + 2*m + 1];
            qs2p[i][m].x = -2.f * a;
            qs2p[i][m].y = -2.f * b;
            qc[2*m]   += a;
            qc[2*m+1] += b;
        }

    // es[j] = sum_k Ss[j][k]*(b2[k]-spec[k]);  c2[m] = es/4 + qc (packed)
    float es[6];
    #pragma unroll
    for (int j = 0; j < 6; ++j) es[j] = 0.f;
    const float* sp = spec + sl * 40;
    for (int k = 0; k < 40; ++k) {
        float v = b2[k] - sp[k];
        #pragma unroll
        for (int j = 0; j < 6; ++j) es[j] = fmaf(v, sSs[j*40+k], es[j]);
    }
    v2f c2[3];
    #pragma unroll
    for (int m = 0; m < 3; ++m) {
        c2[m].x = es[2*m]   * 0.25f + qc[2*m];
        c2[m].y = es[2*m+1] * 0.25f + qc[2*m+1];
    }

    v2f quarter = {0.25f, 0.25f};

    // pin loop-invariants (budget 512 VGPRs at 1 wave/EU)
    #pragma unroll
    for (int j = 0; j < 6; ++j)
        #pragma unroll
        for (int p = 0; p < 8; ++p) pin2(w1kp[j][p]);
    #pragma unroll
    for (int p = 0; p < 8; ++p) pin2(b1kp[p]);
    #pragma unroll
    for (int i = 0; i < 16; ++i)
        #pragma unroll
        for (int m = 0; m < 3; ++m) pin2(qs2p[i][m]);
    #pragma unroll
    for (int m = 0; m < 3; ++m) pin2(c2[m]);
    pin2(quarter);

    // u kept packed: u2[m] = {u[2m], u[2m+1]}
    v2f u2[3];
    #pragma unroll
    for (int m = 0; m < 3; ++m) u2[m] = (v2f){0.5f, 0.5f};

    // one step, phases interleaved across the two 8-unit tiles
    auto do_step = [&]() {
        // tt[p] = b1K + sum_j u[j]*W1K[j], 8 independent chains.
        v2f tt[8];
        #pragma unroll
        for (int p = 0; p < 8; ++p) tt[p] = b1kp[p];
        #pragma unroll
        for (int jp = 0; jp < 3; ++jp) {
            #pragma unroll
            for (int p = 0; p < 8; ++p) { PK_FMA_LO(tt[p], u2[jp], w1kp[2*jp][p]); }
            #pragma unroll
            for (int p = 0; p < 8; ++p) { PK_FMA_HI(tt[p], u2[jp], w1kp[2*jp+1][p]); }
        }
        v2f r2[8];
        #define TRANSP(p)                                                    \
            {                                                                \
                v2f e;                                                       \
                e.x = __builtin_amdgcn_exp2f(tt[p].x);                       \
                e.y = __builtin_amdgcn_exp2f(tt[p].y);                       \
                e += (v2f){1.f, 1.f};                                        \
                r2[p].x = __builtin_amdgcn_rcpf(e.x);                        \
                r2[p].y = __builtin_amdgcn_rcpf(e.y);                        \
            }
        // trans tile0 (pairs 0..3)
        TRANSP(0) TRANSP(1) TRANSP(2) TRANSP(3)
        // gA over units 0..7, with trans tile1 (pairs 4..7) interleaved so
        // the scheduler has FMAs to fill trans shadows and vice versa.
        v2f gA0, gA1, gA2;
        gA0 = __builtin_elementwise_fma(u2[0], quarter, c2[0]);
        gA1 = __builtin_elementwise_fma(u2[1], quarter, c2[1]);
        gA2 = __builtin_elementwise_fma(u2[2], quarter, c2[2]);
        PK_FMA_LO(gA0, r2[0], qs2p[0][0]);
        PK_FMA_LO(gA1, r2[0], qs2p[0][1]);
        PK_FMA_LO(gA2, r2[0], qs2p[0][2]);
        TRANSP(4)
        PK_FMA_HI(gA0, r2[0], qs2p[1][0]);
        PK_FMA_HI(gA1, r2[0], qs2p[1][1]);
        PK_FMA_HI(gA2, r2[0], qs2p[1][2]);
        TRANSP(5)
        PK_FMA_LO(gA0, r2[1], qs2p[2][0]);
        PK_FMA_LO(gA1, r2[1], qs2p[2][1]);
        PK_FMA_LO(gA2, r2[1], qs2p[2][2]);
        TRANSP(6)
        PK_FMA_HI(gA0, r2[1], qs2p[3][0]);
        PK_FMA_HI(gA1, r2[1], qs2p[3][1]);
        PK_FMA_HI(gA2, r2[1], qs2p[3][2]);
        TRANSP(7)
        PK_FMA_LO(gA0, r2[2], qs2p[4][0]);
        PK_FMA_LO(gA1, r2[2], qs2p[4][1]);
        PK_FMA_LO(gA2, r2[2], qs2p[4][2]);
        PK_FMA_HI(gA0, r2[2], qs2p[5][0]);
        PK_FMA_HI(gA1, r2[2], qs2p[5][1]);
        PK_FMA_HI(gA2, r2[2], qs2p[5][2]);
        PK_FMA_LO(gA0, r2[3], qs2p[6][0]);
        PK_FMA_LO(gA1, r2[3], qs2p[6][1]);
        PK_FMA_LO(gA2, r2[3], qs2p[6][2]);
        PK_FMA_HI(gA0, r2[3], qs2p[7][0]);
        PK_FMA_HI(gA1, r2[3], qs2p[7][1]);
        PK_FMA_HI(gA2, r2[3], qs2p[7][2]);
        // gB over units 8..15 (r2[4..7] ready by now)
        v2f gB0, gB1, gB2;
        PK_MUL_LO(gB0, r2[4], qs2p[8][0]);
        PK_MUL_LO(gB1, r2[4], qs2p[8][1]);
        PK_MUL_LO(gB2, r2[4], qs2p[8][2]);
        PK_FMA_HI(gB0, r2[4], qs2p[9][0]);
        PK_FMA_HI(gB1, r2[4], qs2p[9][1]);
        PK_FMA_HI(gB2, r2[4], qs2p[9][2]);
        PK_FMA_LO(gB0, r2[5], qs2p[10][0]);
        PK_FMA_LO(gB1, r2[5], qs2p[10][1]);
        PK_FMA_LO(gB2, r2[5], qs2p[10][2]);
        PK_FMA_HI(gB0, r2[5], qs2p[11][0]);
        PK_FMA_HI(gB1, r2[5], qs2p[11][1]);
        PK_FMA_HI(gB2, r2[5], qs2p[11][2]);
        PK_FMA_LO(gB0, r2[6], qs2p[12][0]);
        PK_FMA_LO(gB1, r2[6], qs2p[12][1]);
        PK_FMA_LO(gB2, r2[6], qs2p[12][2]);
        PK_FMA_HI(gB0, r2[6], qs2p[13][0]);
        PK_FMA_HI(gB1, r2[6], qs2p[13][1]);
        PK_FMA_HI(gB2, r2[6], qs2p[13][2]);
        PK_FMA_LO(gB0, r2[7], qs2p[14][0]);
        PK_FMA_LO(gB1, r2[7], qs2p[14][1]);
        PK_FMA_LO(gB2, r2[7], qs2p[14][2]);
        PK_FMA_HI(gB0, r2[7], qs2p[15][0]);
        PK_FMA_HI(gB1, r2[7], qs2p[15][1]);
        PK_FMA_HI(gB2, r2[7], qs2p[15][2]);
        #undef TRANSP
        // combine halves -> 6 scalars (butterfly inputs)
        v2f h0 = gA0 + gB0, h1 = gA1 + gB1, h2 = gA2 + gB2;
        float a0 = h0.x, a1 = h0.y, a2 = h1.x,
              a3 = h1.y, a4 = h2.x, a5 = h2.y;
        // allreduce over the 4-lane quad: xor1, xor2 (fused DPP adds; 6
        // chains interleaved -> >=5 instrs between dependent stages).
        asm("s_nop 1\n\t"
            "v_add_f32_dpp %0, %0, %0 quad_perm:[1,0,3,2] row_mask:0xf bank_mask:0xf bound_ctrl:0\n\t"
            "v_add_f32_dpp %1, %1, %1 quad_perm:[1,0,3,2] row_mask:0xf bank_mask:0xf bound_ctrl:0\n\t"
            "v_add_f32_dpp %2, %2, %2 quad_perm:[1,0,3,2] row_mask:0xf bank_mask:0xf bound_ctrl:0\n\t"
            "v_add_f32_dpp %3, %3, %3 quad_perm:[1,0,3,2] row_mask:0xf bank_mask:0xf bound_ctrl:0\n\t"
            "v_add_f32_dpp %4, %4, %4 quad_perm:[1,0,3,2] row_mask:0xf bank_mask:0xf bound_ctrl:0\n\t"
            "v_add_f32_dpp %5, %5, %5 quad_perm:[1,0,3,2] row_mask:0xf bank_mask:0xf bound_ctrl:0\n\t"
            "v_add_f32_dpp %0, %0, %0 quad_perm:[2,3,0,1] row_mask:0xf bank_mask:0xf bound_ctrl:0\n\t"
            "v_add_f32_dpp %1, %1, %1 quad_perm:[2,3,0,1] row_mask:0xf bank_mask:0xf bound_ctrl:0\n\t"
            "v_add_f32_dpp %2, %2, %2 quad_perm:[2,3,0,1] row_mask:0xf bank_mask:0xf bound_ctrl:0\n\t"
            "v_add_f32_dpp %3, %3, %3 quad_perm:[2,3,0,1] row_mask:0xf bank_mask:0xf bound_ctrl:0\n\t"
            "v_add_f32_dpp %4, %4, %4 quad_perm:[2,3,0,1] row_mask:0xf bank_mask:0xf bound_ctrl:0\n\t"
            "v_add_f32_dpp %5, %5, %5 quad_perm:[2,3,0,1] row_mask:0xf bank_mask:0xf bound_ctrl:0\n\t"
            : "+v"(a0), "+v"(a1), "+v"(a2), "+v"(a3), "+v"(a4), "+v"(a5));
        u2[0].x = __builtin_amdgcn_fmed3f(a0, 0.f, 1.f);
        u2[0].y = __builtin_amdgcn_fmed3f(a1, 0.f, 1.f);
        u2[1].x = __builtin_amdgcn_fmed3f(a2, 0.f, 1.f);
        u2[1].y = __builtin_amdgcn_fmed3f(a3, 0.f, 1.f);
        u2[2].x = __builtin_amdgcn_fmed3f(a4, 0.f, 1.f);
        u2[2].y = __builtin_amdgcn_fmed3f(a5, 0.f, 1.f);
    };

    // 2-step unroll: bigger scheduling window, half the loop overhead
    for (int step = 0; step < 200; step += 2) {
        do_step();
        do_step();
    }

    if (live && sub == 0) {
        float* o = out + s * 6;
        o[0] = u2[0].x; o[1] = u2[0].y;
        o[2] = u2[1].x; o[3] = u2[1].y;
        o[4] = u2[2].x; o[5] = u2[2].y;
    }
}

extern "C" void kernel_launch(void* const* d_in, const int* in_sizes, int n_in,
                              void* d_out, int out_size, void* d_ws, size_t ws_size,
                              hipStream_t stream)
{
    const float* spec = (const float*)d_in[0];  // (B,40)
    const float* W1   = (const float*)d_in[1];  // (6,64)
    const float* b1   = (const float*)d_in[2];  // (64,)
    const float* W2   = (const float*)d_in[3];  // (64,40)
    const float* b2   = (const float*)d_in[4];  // (40,)
    const float* R    = (const float*)d_in[5];  // (8,40)
    int batch = in_sizes[0] / 40;

    int threads = batch * 4;
    int blocks  = (threads + 255) / 256;
    hipLaunchKernelGGL(solve_k, dim3(blocks), dim3(256), 0, stream,
                       spec, W1, b1, W2, b2, R, (float*)d_out, batch);
}